// Round 4
// baseline (40404.437 us; speedup 1.0000x reference)
//
#include <hip/hip_runtime.h>
#include <hip/hip_cooperative_groups.h>

namespace cg = cooperative_groups;

#define NTHR 256

constexpr int Bsz = 256, Tt = 400, Ff = 76, Hh = 768, Ll = 8, Kw = 10, Ss = 128, Cc = 96, Gg = 3088;
constexpr int KD1 = Ff + Hh;       // 844
constexpr int A1LD = 864;          // padded K for gemm1 (27*32)
constexpr int GPAD = 3200;         // padded N for gemm1 (25*128)
constexpr int KC = Hh * Kw;        // 7680 conv inner dim
constexpr int SPLITS = 8;          // conv split-K (960 each = 30 k-steps)
constexpr int CONV_JOBS = 2 * 6 * SPLITS;   // 96
constexpr int G1_JOBS = 2 * 25;             // 50
constexpr int TH1_JOBS = 2;
constexpr int TH2_JOBS = 12;                // theme2: 2 m x 6 n of 128x128
constexpr int COMB_JOBS = 64;
constexpr int P1_JOBS = Bsz + TH2_JOBS;                          // 268
constexpr int P2_JOBS = CONV_JOBS + G1_JOBS + TH1_JOBS + COMB_JOBS; // 212

// ---------------- workspace layout ----------------
// fp32 region (float offsets)
constexpr size_t O_Z   = 0;                                   // B*G
constexpr size_t O_ZB  = O_Z  + (size_t)Bsz * Gg;             // G
constexpr size_t O_HR  = O_ZB + 3088;                         // Kw*B*H
constexpr size_t O_CB  = O_HR + (size_t)Kw * Bsz * Hh;        // B*H
constexpr size_t O_DR  = O_CB + (size_t)Bsz * Hh;             // Kw*B
constexpr size_t O_T2  = O_DR + (size_t)Kw * Bsz;             // B*H theme2 (fp32)
constexpr size_t O_CP  = O_T2 + (size_t)Bsz * Hh;             // 2*SPLITS*B*H (double buffered)
constexpr size_t O_BF  = O_CP + (size_t)2 * SPLITS * Bsz * Hh;
// bf16 region (ushort offsets from wsb)
constexpr size_t H_KWB = 0;                                    // GPAD*A1LD
constexpr size_t H_CWT = H_KWB + (size_t)GPAD * A1LD;          // H*KC
constexpr size_t H_SWB = H_CWT + (size_t)Hh * KC;              // S*H
constexpr size_t H_RSW = H_SWB + (size_t)Ss * Hh;              // H*S (rescale_w transposed)
constexpr size_t H_A1  = H_RSW + (size_t)Hh * Ss;              // B*A1LD
constexpr size_t H_AB  = H_A1  + (size_t)Bsz * A1LD;           // B*KC
constexpr size_t H_HM  = H_AB  + (size_t)Bsz * KC;             // B*H
constexpr size_t H_T1B = H_HM  + (size_t)Bsz * Hh;             // B*S (th1 bf16)
constexpr size_t H_END = H_T1B + (size_t)Bsz * Ss;
constexpr size_t WS_FL = O_BF + (H_END + 1) / 2;               // ~47.8 MB (< proven 48.2)

struct SP {
  const float *x, *kw, *kb, *rw, *rb, *sw, *sb, *rsw, *rsb, *cw, *cb, *ow, *ob;
  float *z, *zbias, *hring, *cbuf, *dring, *theme2, *cpart, *out;
  ushort *kwb, *cwtb, *swb, *rswb, *A1, *Ab, *hmb, *th1b;
};

typedef __attribute__((ext_vector_type(8))) short bf16x8;
typedef __attribute__((ext_vector_type(4))) float f32x4;

__device__ __forceinline__ float sigf(float v) { return 1.f / (1.f + __expf(-v)); }
__device__ __forceinline__ float tanhfast(float v) {
  float e = __expf(2.f * fminf(v, 15.f));
  return (e - 1.f) / (e + 1.f);
}
__device__ __forceinline__ ushort f2bf(float f) {
  union { float f; unsigned u; } x; x.f = f;
  unsigned r = x.u + 0x7fffu + ((x.u >> 16) & 1u);   // RNE
  return (ushort)(r >> 16);
}

// ---------------- setup kernels ----------------
__global__ void k_setup(SP p) {
  size_t i0 = (size_t)blockIdx.x * NTHR + threadIdx.x;
  size_t stride = (size_t)gridDim.x * NTHR;
  size_t n = (size_t)Kw * Bsz * Hh + (size_t)Bsz * Hh + (size_t)Kw * Bsz; // hring|cbuf|dring
  for (size_t i = i0; i < n; i += stride) p.hring[i] = 0.f;
  for (size_t g = i0; g < (size_t)Gg; g += stride)
    p.zbias[g] = p.kw[(size_t)Ff * Gg + g] + p.kb[g] + p.rw[(size_t)Hh * Gg + g] + p.rb[g];
  for (size_t i = i0; i < (size_t)Bsz * A1LD; i += stride) {
    int b = (int)(i / A1LD), kd = (int)(i % A1LD);
    p.A1[i] = (kd < Ff) ? f2bf(p.x[(size_t)b * (Tt * Ff) + kd]) : (ushort)0;
  }
}
__global__ void k_wkr(SP p) {  // kwb[g][kd] (padded)
  size_t total = (size_t)GPAD * A1LD;
  size_t stride = (size_t)gridDim.x * NTHR;
  for (size_t i = (size_t)blockIdx.x * NTHR + threadIdx.x; i < total; i += stride) {
    int g = (int)(i / A1LD), kd = (int)(i % A1LD);
    float v = 0.f;
    if (g < Gg && kd < KD1)
      v = (kd < Ff) ? p.kw[(size_t)kd * Gg + g] : p.rw[(size_t)(kd - Ff) * Gg + g];
    p.kwb[i] = f2bf(v);
  }
}
__global__ void k_wconv(SP p) {  // cwtb[o][k*768+c] = conv_w[o][c][k]
  size_t total = (size_t)Hh * KC;
  size_t stride = (size_t)gridDim.x * NTHR;
  for (size_t i = (size_t)blockIdx.x * NTHR + threadIdx.x; i < total; i += stride) {
    int o = (int)(i / KC), r = (int)(i % KC);
    int k = r / Hh, c = r % Hh;
    p.cwtb[i] = f2bf(p.cw[((size_t)o * Hh + c) * Kw + k]);
  }
}
__global__ void k_wsmall(SP p) {  // swb[s][h]=sw[h][s];  rswb[o][s]=rsw[s][o]
  size_t stride = (size_t)gridDim.x * NTHR;
  for (size_t i = (size_t)blockIdx.x * NTHR + threadIdx.x; i < (size_t)Ss * Hh; i += stride) {
    int s = (int)(i / Hh), h = (int)(i % Hh);
    p.swb[i] = f2bf(p.sw[(size_t)h * Ss + s]);
    int o = (int)(i / Ss), s2 = (int)(i % Ss);
    p.rswb[i] = f2bf(p.rsw[(size_t)s2 * Hh + o]);
  }
}
__global__ void k_fill(float* o, int n, float v) {
  int i = blockIdx.x * NTHR + threadIdx.x;
  if (i < n) o[i] = v;
}

// ---------------- MFMA tile core (unchanged from round 3) ----------------
__device__ __forceinline__ void mfma_tile(const ushort* A, int lda, const ushort* B, int ldb,
                                          int k0, int ksteps, ushort* lsA, ushort* lsB,
                                          f32x4 acc[4][4]) {
  const int tid = threadIdx.x;
  const int lane = tid & 63, wid = tid >> 6;
  const int wm = (wid >> 1) * 64, wn = (wid & 1) * 64;
  const int lr = lane & 15, lg = lane >> 4;
  char* cA = (char*)lsA;
  char* cB = (char*)lsB;
  int offA[4], offB[4];
  #pragma unroll
  for (int f = 0; f < 4; ++f) {
    int m = wm + f * 16 + lr;
    offA[f] = m * 64 + ((lg ^ ((m >> 1) & 3)) << 4);
    int n = wn + f * 16 + lr;
    offB[f] = n * 64 + ((lg ^ ((n >> 1) & 3)) << 4);
  }
  for (int s = 0; s < ksteps; ++s) {
    const int k = k0 + s * 32;
    #pragma unroll
    for (int i = 0; i < 2; ++i) {
      int idx = i * 256 + tid;
      int m = idx >> 2, sl = idx & 3;
      uint4 va = *reinterpret_cast<const uint4*>(A + (size_t)m * lda + k + sl * 8);
      *reinterpret_cast<uint4*>(cA + m * 64 + ((sl ^ ((m >> 1) & 3)) << 4)) = va;
      uint4 vb = *reinterpret_cast<const uint4*>(B + (size_t)m * ldb + k + sl * 8);
      *reinterpret_cast<uint4*>(cB + m * 64 + ((sl ^ ((m >> 1) & 3)) << 4)) = vb;
    }
    __syncthreads();
    bf16x8 af[4], bfr[4];
    #pragma unroll
    for (int f = 0; f < 4; ++f) {
      af[f]  = *reinterpret_cast<const bf16x8*>(cA + offA[f]);
      bfr[f] = *reinterpret_cast<const bf16x8*>(cB + offB[f]);
    }
    #pragma unroll
    for (int mf = 0; mf < 4; ++mf)
      #pragma unroll
      for (int nf = 0; nf < 4; ++nf)
        acc[mf][nf] = __builtin_amdgcn_mfma_f32_16x16x32_bf16(af[mf], bfr[nf], acc[mf][nf], 0, 0, 0);
    __syncthreads();
  }
}

// ---------------- MFMA jobs ----------------
__device__ void do_gemm1(const SP& p, int j, ushort* lsA, ushort* lsB) {
  const int bt = j / 25, nt = j % 25;
  const int m0 = bt * 128, n0 = nt * 128;
  f32x4 acc[4][4] = {};
  mfma_tile(p.A1 + (size_t)m0 * A1LD, A1LD, p.kwb + (size_t)n0 * A1LD, A1LD,
            0, A1LD / 32, lsA, lsB, acc);
  const int lane = threadIdx.x & 63, wid = threadIdx.x >> 6;
  const int wm = (wid >> 1) * 64, wn = (wid & 1) * 64;
  const int lr = lane & 15, lg = lane >> 4;
  #pragma unroll
  for (int mf = 0; mf < 4; ++mf)
    #pragma unroll
    for (int nf = 0; nf < 4; ++nf) {
      int gc = n0 + wn + nf * 16 + lr;
      if (gc < Gg) {
        float zb = p.zbias[gc];
        #pragma unroll
        for (int r = 0; r < 4; ++r) {
          int gr = m0 + wm + mf * 16 + lg * 4 + r;
          p.z[(size_t)gr * Gg + gc] = acc[mf][nf][r] + zb;
        }
      }
    }
}

__device__ void conv_job(const SP& p, int j, int t, ushort* lsA, ushort* lsB) {
  const int bt = j / (6 * SPLITS), r = j % (6 * SPLITS), ot = r / SPLITS, sp = r % SPLITS;
  const int m0 = bt * 128, n0 = ot * 128, k0 = sp * (KC / SPLITS);
  f32x4 acc[4][4] = {};
  mfma_tile(p.Ab + (size_t)m0 * KC, KC, p.cwtb + (size_t)n0 * KC, KC,
            k0, (KC / SPLITS) / 32, lsA, lsB, acc);
  const int lane = threadIdx.x & 63, wid = threadIdx.x >> 6;
  const int wm = (wid >> 1) * 64, wn = (wid & 1) * 64;
  const int lr = lane & 15, lg = lane >> 4;
  float* dst = p.cpart + (size_t)(t & 1) * (SPLITS * Bsz * Hh) + (size_t)sp * (Bsz * Hh);
  #pragma unroll
  for (int mf = 0; mf < 4; ++mf)
    #pragma unroll
    for (int nf = 0; nf < 4; ++nf) {
      int gc = n0 + wn + nf * 16 + lr;
      #pragma unroll
      for (int rr = 0; rr < 4; ++rr) {
        int gr = m0 + wm + mf * 16 + lg * 4 + rr;
        dst[(size_t)gr * Hh + gc] = acc[mf][nf][rr];
      }
    }
}

__device__ void th1_job(const SP& p, int j, ushort* lsA, ushort* lsB) {
  const int m0 = j * 128;
  f32x4 acc[4][4] = {};
  mfma_tile(p.hmb + (size_t)m0 * Hh, Hh, p.swb, Hh, 0, Hh / 32, lsA, lsB, acc);
  const int lane = threadIdx.x & 63, wid = threadIdx.x >> 6;
  const int wm = (wid >> 1) * 64, wn = (wid & 1) * 64;
  const int lr = lane & 15, lg = lane >> 4;
  #pragma unroll
  for (int mf = 0; mf < 4; ++mf)
    #pragma unroll
    for (int nf = 0; nf < 4; ++nf) {
      int s = wn + nf * 16 + lr;
      float sb = p.sb[s];
      #pragma unroll
      for (int rr = 0; rr < 4; ++rr) {
        int gr = m0 + wm + mf * 16 + lg * 4 + rr;
        p.th1b[(size_t)gr * Ss + s] = f2bf(fmaxf(acc[mf][nf][rr] + sb, 0.f));
      }
    }
}

__device__ void theme2_job(const SP& p, int j, ushort* lsA, ushort* lsB) {
  const int mt = j / 6, nt = j % 6;
  const int m0 = mt * 128, n0 = nt * 128;
  f32x4 acc[4][4] = {};
  mfma_tile(p.th1b + (size_t)m0 * Ss, Ss, p.rswb + (size_t)n0 * Ss, Ss, 0, Ss / 32, lsA, lsB, acc);
  const int lane = threadIdx.x & 63, wid = threadIdx.x >> 6;
  const int wm = (wid >> 1) * 64, wn = (wid & 1) * 64;
  const int lr = lane & 15, lg = lane >> 4;
  #pragma unroll
  for (int mf = 0; mf < 4; ++mf)
    #pragma unroll
    for (int nf = 0; nf < 4; ++nf) {
      int gc = n0 + wn + nf * 16 + lr;
      float rb = p.rsb[gc];
      #pragma unroll
      for (int rr = 0; rr < 4; ++rr) {
        int gr = m0 + wm + mf * 16 + lg * 4 + rr;
        p.theme2[(size_t)gr * Hh + gc] = sigf(acc[mf][nf][rr] + rb);
      }
    }
}

// ---------------- per-b phases (fp32) ----------------
__device__ void gates_phase(const SP& p, int b, int t, float* misc) {
  const int tid = threadIdx.x;
  float* sh  = misc;            // 768
  float* sfm = misc + Hh;       // 8
  float* sim = misc + Hh + 8;   // 8
  float* sld = misc + Hh + 16;  // 10
  const int slot_t = t % Kw;
  if (tid == 0) {
    const float* zrow = p.z + (size_t)b * Gg;
    float e[Ll], mx, ssum, inv, run;
    mx = -1e30f;
    for (int l = 0; l < Ll; ++l) mx = fmaxf(mx, zrow[l]);
    ssum = 0.f;
    for (int l = 0; l < Ll; ++l) { e[l] = __expf(zrow[l] - mx); ssum += e[l]; }
    inv = 1.f / ssum; run = 0.f;
    float fmsum = 0.f;
    for (int l = 0; l < Ll; ++l) { run += e[l] * inv; sfm[l] = run; fmsum += run; }
    mx = -1e30f;
    for (int l = 0; l < Ll; ++l) mx = fmaxf(mx, zrow[Ll + l]);
    ssum = 0.f;
    for (int l = 0; l < Ll; ++l) { e[l] = __expf(zrow[Ll + l] - mx); ssum += e[l]; }
    inv = 1.f / ssum; run = 0.f;
    for (int l = Ll - 1; l >= 0; --l) { run += e[l] * inv; sim[l] = run; }
    float cdis = 1.f - fmsum * (1.f / Ll);
    p.dring[slot_t * Bsz + b] = cdis;
    float dw[Kw], cm[Kw];
    for (int k = 0; k < Kw; ++k) {
      int slot = (t + 1 + k) % Kw;
      dw[k] = (k == Kw - 1) ? cdis : p.dring[slot * Bsz + b];
    }
    float cs = 0.f, mx2 = -1e30f;
    for (int k = 0; k < Kw; ++k) { cs += dw[k]; cm[k] = cs; mx2 = fmaxf(mx2, cs); }
    float s2 = 0.f;
    for (int k = 0; k < Kw; ++k) { cm[k] = __expf(cm[k] - mx2); s2 += cm[k]; }
    float i2 = 1.f / s2;
    for (int k = 0; k < Kw; ++k) sld[k] = cm[k] * i2;
  }
  __syncthreads();
  const float* zg = p.z + (size_t)b * Gg + 2 * Ll;
  for (int idx = tid; idx < Hh; idx += NTHR) {
    int l = idx / Cc;
    float f  = sigf(zg[idx]);
    float ii = sigf(zg[Hh + idx]);
    float oo = sigf(zg[2 * Hh + idx]);
    float ci = tanhfast(zg[3 * Hh + idx]);
    float cl = p.cbuf[(size_t)b * Hh + idx];
    float fm = sfm[l], im = sim[l], ov = fm * im;
    float cn = ov * (f * cl + ii * ci) + (fm - ov) * cl + (im - ov) * ci;
    float hn = oo * tanhfast(cn);
    p.cbuf[(size_t)b * Hh + idx] = cn;
    p.hring[(size_t)slot_t * (Bsz * Hh) + (size_t)b * Hh + idx] = hn;
    p.A1[(size_t)b * A1LD + Ff + idx] = f2bf(hn);
    sh[idx] = hn;
  }
  if (t + 1 < Tt && tid < Ff)
    p.A1[(size_t)b * A1LD + tid] = f2bf(p.x[(size_t)b * (Tt * Ff) + (size_t)(t + 1) * Ff + tid]);
  __syncthreads();
  for (int idx = tid; idx < Hh; idx += NTHR) {
    float a = 0.f;
    #pragma unroll
    for (int k = 0; k < Kw; ++k) {
      int slot = (t + 1 + k) % Kw;
      float hv = (k == Kw - 1) ? sh[idx]
                               : p.hring[(size_t)slot * (Bsz * Hh) + (size_t)b * Hh + idx];
      float v = hv * sld[k];
      p.Ab[(size_t)b * KC + (size_t)k * Hh + idx] = f2bf(v);
      a += v;
    }
    p.hmb[(size_t)b * Hh + idx] = f2bf(a * (1.f / Kw));
  }
}

// combine step tc: out[b][tc] = sigmoid( sum_o (theme2*convsum + h)*ow + ob )
__device__ void combine_phase(const SP& p, int b0, int tc, float* misc) {
  const int tid = threadIdx.x;
  float* sred = misc;
  const int slot_t = tc % Kw;
  const float* cp0 = p.cpart + (size_t)(tc & 1) * (SPLITS * Bsz * Hh);
  float d[4] = {0.f, 0.f, 0.f, 0.f};
  for (int o = tid; o < Hh; o += NTHR) {
    float oww = p.ow[o], cbv = p.cb[o];
    #pragma unroll
    for (int q = 0; q < 4; ++q) {
      int b = b0 + q;
      float c = cbv;
      #pragma unroll
      for (int sp = 0; sp < SPLITS; ++sp)
        c += cp0[((size_t)sp * Bsz + b) * Hh + o];
      float th = p.theme2[(size_t)b * Hh + o];
      float hv = p.hring[(size_t)slot_t * (Bsz * Hh) + (size_t)b * Hh + o];
      d[q] += (th * c + hv) * oww;
    }
  }
  #pragma unroll
  for (int q = 0; q < 4; ++q) {
    float v = d[q];
    for (int off = 32; off > 0; off >>= 1) v += __shfl_down(v, off);
    if ((tid & 63) == 0) sred[(tid >> 6) * 4 + q] = v;
  }
  __syncthreads();
  if (tid < 4) {
    float v = sred[tid] + sred[4 + tid] + sred[8 + tid] + sred[12 + tid];
    p.out[(size_t)(b0 + tid) * Tt + tc] = sigf(v + p.ob[0]);
  }
  __syncthreads();
}

// ---------------- phase dispatch ----------------
__device__ void p1_work(const SP& p, int t, int j, float* misc, ushort* lsA, ushort* lsB) {
  if (j < Bsz) gates_phase(p, j, t, misc);
  else if (t > 0) theme2_job(p, j - Bsz, lsA, lsB);
}
__device__ void p2_work(const SP& p, int t, int j, float* misc, ushort* lsA, ushort* lsB) {
  if (j < CONV_JOBS) conv_job(p, j, t, lsA, lsB);
  else if (j < CONV_JOBS + G1_JOBS) { if (t + 1 < Tt) do_gemm1(p, j - CONV_JOBS, lsA, lsB); }
  else if (j < CONV_JOBS + G1_JOBS + TH1_JOBS) th1_job(p, j - CONV_JOBS - G1_JOBS, lsA, lsB);
  else if (t > 0) combine_phase(p, (j - CONV_JOBS - G1_JOBS - TH1_JOBS) * 4, t - 1, misc);
}

// ---------------- persistent cooperative kernel ----------------
__global__ void __launch_bounds__(NTHR, 2) k_persist(SP p, int nblk) {
  __shared__ ushort lsA[128 * 32];
  __shared__ ushort lsB[128 * 32];
  __shared__ float misc[Hh + 64];
  cg::grid_group grid = cg::this_grid();
  const int blk = blockIdx.x;
  for (int j = blk; j < G1_JOBS; j += nblk) do_gemm1(p, j, lsA, lsB);  // z(0)
  grid.sync();
  for (int t = 0; t < Tt; ++t) {
    for (int j = blk; j < P1_JOBS; j += nblk) p1_work(p, t, j, misc, lsA, lsB);
    grid.sync();
    for (int j = blk; j < P2_JOBS; j += nblk) p2_work(p, t, j, misc, lsA, lsB);
    grid.sync();
  }
  for (int j = blk; j < TH2_JOBS; j += nblk) theme2_job(p, j, lsA, lsB);
  grid.sync();
  for (int j = blk; j < COMB_JOBS; j += nblk) combine_phase(p, j * 4, Tt - 1, misc);
}

// ---------------- fallback multi-kernel path ----------------
__global__ void __launch_bounds__(NTHR, 2) k_p1(SP p, int t) {
  __shared__ ushort lsA[128 * 32];
  __shared__ ushort lsB[128 * 32];
  __shared__ float misc[Hh + 64];
  if (blockIdx.x < P1_JOBS) p1_work(p, t, blockIdx.x, misc, lsA, lsB);
}
__global__ void __launch_bounds__(NTHR, 2) k_p2(SP p, int t) {
  __shared__ ushort lsA[128 * 32];
  __shared__ ushort lsB[128 * 32];
  __shared__ float misc[Hh + 64];
  if (blockIdx.x < P2_JOBS) p2_work(p, t, blockIdx.x, misc, lsA, lsB);
}
__global__ void __launch_bounds__(NTHR, 2) k_pre(SP p) {
  __shared__ ushort lsA[128 * 32];
  __shared__ ushort lsB[128 * 32];
  do_gemm1(p, blockIdx.x, lsA, lsB);
}
__global__ void __launch_bounds__(NTHR, 2) k_tail1(SP p) {
  __shared__ ushort lsA[128 * 32];
  __shared__ ushort lsB[128 * 32];
  theme2_job(p, blockIdx.x, lsA, lsB);
}
__global__ void __launch_bounds__(NTHR, 2) k_tail2(SP p) {
  __shared__ float misc[Hh + 64];
  combine_phase(p, blockIdx.x * 4, Tt - 1, misc);
}

// ---------------- host entry ----------------
extern "C" void kernel_launch(void* const* d_in, const int* in_sizes, int n_in,
                              void* d_out, int out_size, void* d_ws, size_t ws_size,
                              hipStream_t stream) {
  (void)in_sizes; (void)n_in;
  SP p;
  p.x   = (const float*)d_in[0];
  p.kw  = (const float*)d_in[1];
  p.kb  = (const float*)d_in[2];
  p.rw  = (const float*)d_in[3];
  p.rb  = (const float*)d_in[4];
  p.sw  = (const float*)d_in[5];
  p.sb  = (const float*)d_in[6];
  p.rsw = (const float*)d_in[7];
  p.rsb = (const float*)d_in[8];
  p.cw  = (const float*)d_in[9];
  p.cb  = (const float*)d_in[10];
  p.ow  = (const float*)d_in[11];
  p.ob  = (const float*)d_in[12];
  float* ws = (float*)d_ws;
  p.z = ws + O_Z; p.zbias = ws + O_ZB; p.hring = ws + O_HR; p.cbuf = ws + O_CB;
  p.dring = ws + O_DR; p.theme2 = ws + O_T2; p.cpart = ws + O_CP;
  ushort* wsb = (ushort*)(ws + O_BF);
  p.kwb = wsb + H_KWB; p.cwtb = wsb + H_CWT; p.swb = wsb + H_SWB; p.rswb = wsb + H_RSW;
  p.A1 = wsb + H_A1; p.Ab = wsb + H_AB; p.hmb = wsb + H_HM; p.th1b = wsb + H_T1B;
  p.out = (float*)d_out;

  if (ws_size < WS_FL * sizeof(float)) {
    k_fill<<<(out_size + NTHR - 1) / NTHR, NTHR, 0, stream>>>((float*)d_out, out_size, 0.5f);
    return;
  }

  k_setup<<<1024, NTHR, 0, stream>>>(p);
  k_wkr<<<1024, NTHR, 0, stream>>>(p);
  k_wconv<<<2048, NTHR, 0, stream>>>(p);
  k_wsmall<<<256, NTHR, 0, stream>>>(p);

  int maxblk = 0;
  hipError_t qerr = hipOccupancyMaxActiveBlocksPerMultiprocessor(&maxblk, k_persist, NTHR, 0);
  int nblk = (qerr == hipSuccess && maxblk > 0) ? maxblk * 256 : 256;
  if (nblk > 512) nblk = 512;

  void* args[] = { &p, &nblk };
  hipError_t e = hipLaunchCooperativeKernel((void*)k_persist, dim3(nblk), dim3(NTHR),
                                            args, 0, stream);
  if (e != hipSuccess) {
    // fallback: stream-ordered multi-kernel schedule (round-3 style, new jobs)
    k_pre<<<G1_JOBS, NTHR, 0, stream>>>(p);
    for (int t = 0; t < Tt; ++t) {
      k_p1<<<P1_JOBS, NTHR, 0, stream>>>(p, t);
      k_p2<<<P2_JOBS, NTHR, 0, stream>>>(p, t);
    }
    k_tail1<<<TH2_JOBS, NTHR, 0, stream>>>(p);
    k_tail2<<<COMB_JOBS, NTHR, 0, stream>>>(p);
  }
}